// Round 2
// baseline (1173.270 us; speedup 1.0000x reference)
//
#include <hip/hip_runtime.h>
#include <math.h>

// CrossAttention  B=32, S=1024, D_MODEL=48, NUM_HEADS=3, D_K=16
// Outputs: H [32,1024,48] ++ A [32,3,1024,1024], fp32.

#define NROWS   32768      // B*S
#define HW_SZ   1572864L   // 96*1024*16 floats per Q/K/V/Hh buffer

__device__ __forceinline__ void load16(const float* __restrict__ p, float* r) {
    float4 a = ((const float4*)p)[0];
    float4 b = ((const float4*)p)[1];
    float4 c = ((const float4*)p)[2];
    float4 d = ((const float4*)p)[3];
    r[0]=a.x;  r[1]=a.y;  r[2]=a.z;  r[3]=a.w;
    r[4]=b.x;  r[5]=b.y;  r[6]=b.z;  r[7]=b.w;
    r[8]=c.x;  r[9]=c.y;  r[10]=c.z; r[11]=c.w;
    r[12]=d.x; r[13]=d.y; r[14]=d.z; r[15]=d.w;
}

// ---------------- Kernel 1: fused Q/K/V projections ----------------
// Block = 192 threads, 32 rows/block (8 groups of 4 rows). Weights staged once.
__global__ __launch_bounds__(192) void proj_qkv(
    const float* __restrict__ Xq, const float* __restrict__ Xk, const float* __restrict__ Xv,
    const float* __restrict__ Wq, const float* __restrict__ bq,
    const float* __restrict__ Wk, const float* __restrict__ bk,
    const float* __restrict__ Wv, const float* __restrict__ bv,
    float* __restrict__ Qo, float* __restrict__ Ko, float* __restrict__ Vo)
{
    __shared__ float Wls[3][48][49];
    __shared__ float bls[3][48];
    __shared__ float Xls[3][32][48];
    const int t = threadIdx.x;

    for (int f = t; f < 3*48*48; f += 192) {
        int m = f / 2304, rem = f % 2304, r = rem / 48, c = rem % 48;
        const float* W = (m == 0) ? Wq : ((m == 1) ? Wk : Wv);
        Wls[m][r][c] = W[r*48 + c];
    }
    if (t < 144) {
        int m = t / 48, c = t % 48;
        const float* bb = (m == 0) ? bq : ((m == 1) ? bk : bv);
        bls[m][c] = bb[c];
    }
    const long row0 = (long)blockIdx.x * 32;
    // Stage 3*32*48 floats = 1152 float4; 6 per thread, coalesced.
    for (int f = t; f < 1152; f += 192) {
        int m = f / 384, ff = f % 384, r = ff / 12, p = ff % 12;
        const float* X = (m == 0) ? Xq : ((m == 1) ? Xk : Xv);
        float4 v = *(const float4*)(X + (row0 + r)*48 + p*4);
        *(float4*)&Xls[m][r][p*4] = v;
    }
    __syncthreads();

    const int rb = t / 48, j = t % 48;
    const int h = j >> 4, d = j & 15;
#pragma unroll
    for (int rl = 0; rl < 8; rl++) {
        const int r = rl*4 + rb;
        float aq = bls[0][j], ak = bls[1][j], av = bls[2][j];
#pragma unroll
        for (int i = 0; i < 48; i++) {
            aq += Xls[0][r][i] * Wls[0][j][i];
            ak += Xls[1][r][i] * Wls[1][j][i];
            av += Xls[2][r][i] * Wls[2][j][i];
        }
        const long srow = row0 + r;
        const long b = srow >> 10, sp = srow & 1023;
        const long idx = (((b*3 + h) << 10) + sp)*16 + d;
        Qo[idx] = aq; Ko[idx] = ak; Vo[idx] = av;
    }
}

// ---------------- Kernel 2: fused attention ----------------
// Block = 256 threads = 16 q-rows x 16 k-lanes. NO LDS, NO barriers.
// Lane kl owns k-rows k ≡ kl (mod 16): loads them straight from global
// (L2-hot: 128 KB K/V panel per bh, shared by 64 blocks on one XCD).
// PV needs no cross-lane exchange: lane kl owns s[k] for exactly its V-rows.
// s[64] is FULLY statically indexed (all k-loops fully unrolled) so it
// lives in VGPRs -- the previous version's runtime-indexed s[] spilled to
// scratch (~1.2 GB of hidden HBM traffic = the WRITE_SIZE mystery).
// A is written with nontemporal stores: 402 MB of write-once data must not
// thrash L2 (it was evicting K/V panels and the scratch lines).
__global__ __launch_bounds__(256) void attn(
    const float* __restrict__ Q, const float* __restrict__ K, const float* __restrict__ V,
    float* __restrict__ A, float* __restrict__ Hh)
{
    // XCD-aware bijective swizzle: 6144 blocks, 8 XCDs, 768 per XCD.
    const int blk  = blockIdx.x;
    const int virt = (blk & 7) * 768 + (blk >> 3);
    const int bh   = virt >> 6;    // 0..95
    const int qt   = virt & 63;
    const int t    = threadIdx.x;
    const int qg   = t >> 4;       // 0..15 query row in tile
    const int kl   = t & 15;       // 0..15 k-lane

    const long base = (long)bh * 1024 * 16;
    const int  q    = qt * 16 + qg;

    float qv[16];
    load16(Q + base + (long)q * 16, qv);
#pragma unroll
    for (int d = 0; d < 16; d++) qv[d] *= 0.25f;   // 1/sqrt(16)

    const float4* __restrict__ Kr = (const float4*)(K + base);
    const float4* __restrict__ Vr = (const float4*)(V + base);

    // ---- Phase 1: scores. s[x] = q . K[x*16+kl], fully unrolled. ----
    float s[64];
#pragma unroll
    for (int x = 0; x < 64; x++) {
        const int r = x*16 + kl;
        float4 a = Kr[r*4+0];
        float4 b = Kr[r*4+1];
        float4 c = Kr[r*4+2];
        float4 d = Kr[r*4+3];
        s[x] = qv[0]*a.x  + qv[1]*a.y  + qv[2]*a.z  + qv[3]*a.w
             + qv[4]*b.x  + qv[5]*b.y  + qv[6]*b.z  + qv[7]*b.w
             + qv[8]*c.x  + qv[9]*c.y  + qv[10]*c.z + qv[11]*c.w
             + qv[12]*d.x + qv[13]*d.y + qv[14]*d.z + qv[15]*d.w;
    }

    // ---- softmax across the 16-lane q-group ----
    float m = -1e30f;
#pragma unroll
    for (int x = 0; x < 64; x++) m = fmaxf(m, s[x]);
#pragma unroll
    for (int mask = 1; mask < 16; mask <<= 1) m = fmaxf(m, __shfl_xor(m, mask, 16));
    float l = 0.f;
#pragma unroll
    for (int x = 0; x < 64; x++) { s[x] = __expf(s[x] - m); l += s[x]; }
#pragma unroll
    for (int mask = 1; mask < 16; mask <<= 1) l += __shfl_xor(l, mask, 16);
    const float inv = 1.0f / l;
#pragma unroll
    for (int x = 0; x < 64; x++) s[x] *= inv;

    // ---- Phase 2: write A (nontemporal) + accumulate PV from global V ----
    float o[16];
#pragma unroll
    for (int d = 0; d < 16; d++) o[d] = 0.f;
    float* Arow = A + ((long)bh * 1024 + q) * 1024;

#pragma unroll
    for (int x = 0; x < 64; x++) {
        const int r = x*16 + kl;
        float4 a = Vr[r*4+0];
        float4 b = Vr[r*4+1];
        float4 c = Vr[r*4+2];
        float4 d = Vr[r*4+3];
        const float p = s[x];
        __builtin_nontemporal_store(p, Arow + r);
        o[0]  += p*a.x;  o[1]  += p*a.y;  o[2]  += p*a.z;  o[3]  += p*a.w;
        o[4]  += p*b.x;  o[5]  += p*b.y;  o[6]  += p*b.z;  o[7]  += p*b.w;
        o[8]  += p*c.x;  o[9]  += p*c.y;  o[10] += p*c.z;  o[11] += p*c.w;
        o[12] += p*d.x;  o[13] += p*d.y;  o[14] += p*d.z;  o[15] += p*d.w;
    }

#pragma unroll
    for (int mask = 1; mask < 16; mask <<= 1) {
#pragma unroll
        for (int d = 0; d < 16; d++) o[d] += __shfl_xor(o[d], mask, 16);
    }
    Hh[base + (long)q * 16 + kl] = o[kl];
}

// ---------------- Kernel 3: output projection ----------------
__global__ __launch_bounds__(192) void proj_out(
    const float* __restrict__ Hh, const float* __restrict__ Wh, const float* __restrict__ bhp,
    float* __restrict__ Hout)
{
    __shared__ float Wls[48][49];
    __shared__ float bls[48];
    __shared__ float Hls[32][48];
    const int t = threadIdx.x;

    for (int f = t; f < 2304; f += 192) Wls[f/48][f%48] = Wh[f];
    if (t < 48) bls[t] = bhp[t];
    const long row0 = (long)blockIdx.x * 32;
    for (int f = t; f < 1536; f += 192) {
        int r = f / 48, col = f % 48;
        long srow = row0 + r;
        long b = srow >> 10, sp = srow & 1023;
        Hls[r][col] = Hh[(((b*3 + (col >> 4)) << 10) + sp)*16 + (col & 15)];
    }
    __syncthreads();

    const int rb = t / 48, j = t % 48;
#pragma unroll
    for (int rl = 0; rl < 8; rl++) {
        const int r = rl*4 + rb;
        float acc = bls[j];
#pragma unroll
        for (int i = 0; i < 48; i++) acc += Hls[r][i] * Wls[j][i];
        Hout[(row0 + r)*48 + j] = acc;
    }
}

extern "C" void kernel_launch(void* const* d_in, const int* in_sizes, int n_in,
                              void* d_out, int out_size, void* d_ws, size_t ws_size,
                              hipStream_t stream) {
    const float* Xq = (const float*)d_in[0];
    const float* Xk = (const float*)d_in[1];
    const float* Xv = (const float*)d_in[2];
    const float* Wq = (const float*)d_in[3];
    const float* bq = (const float*)d_in[4];
    const float* Wk = (const float*)d_in[5];
    const float* bk = (const float*)d_in[6];
    const float* Wv = (const float*)d_in[7];
    const float* bv = (const float*)d_in[8];
    const float* Wh = (const float*)d_in[9];
    const float* bh = (const float*)d_in[10];

    float* out = (float*)d_out;
    float* Hout = out;                    // [32,1024,48]
    float* Aout = out + HW_SZ;            // [32,3,1024,1024]

    float* ws = (float*)d_ws;
    float* Qw = ws;
    float* Kw = ws + HW_SZ;
    float* Vw = ws + 2*HW_SZ;
    float* Hw = ws + 3*HW_SZ;

    proj_qkv<<<NROWS/32, 192, 0, stream>>>(Xq, Xk, Xv, Wq, bq, Wk, bk, Wv, bv, Qw, Kw, Vw);
    attn<<<96*64, 256, 0, stream>>>(Qw, Kw, Vw, Aout, Hw);
    proj_out<<<NROWS/32, 192, 0, stream>>>(Hw, Wh, bh, Hout);
}

// Round 3
// 695.040 us; speedup vs baseline: 1.6881x; 1.6881x over previous
//
#include <hip/hip_runtime.h>
#include <math.h>

// CrossAttention  B=32, S=1024, D_MODEL=48, NUM_HEADS=3, D_K=16
// Outputs: H [32,1024,48] ++ A [32,3,1024,1024], fp32.

#define NROWS   32768      // B*S
#define HW_SZ   1572864L   // 96*1024*16 floats per Q/K/V/Hh buffer
#define PITCH   20         // LDS row pitch (floats): 2-way bank aliasing = free

__device__ __forceinline__ void load16(const float* __restrict__ p, float* r) {
    float4 a = ((const float4*)p)[0];
    float4 b = ((const float4*)p)[1];
    float4 c = ((const float4*)p)[2];
    float4 d = ((const float4*)p)[3];
    r[0]=a.x;  r[1]=a.y;  r[2]=a.z;  r[3]=a.w;
    r[4]=b.x;  r[5]=b.y;  r[6]=b.z;  r[7]=b.w;
    r[8]=c.x;  r[9]=c.y;  r[10]=c.z; r[11]=c.w;
    r[12]=d.x; r[13]=d.y; r[14]=d.z; r[15]=d.w;
}

// ---------------- Projection row worker ----------------
// One thread = one sequence row. X row held in 48 VGPRs; W/bias accessed at
// wave-uniform compile-time offsets -> scalar (SGPR) loads, broadcast free.
// 2304 FMAs per matrix with 16-way ILP; no LDS at all.
__device__ __forceinline__ void proj_row(
    const float* __restrict__ X, const float* __restrict__ W,
    const float* __restrict__ bias, float* __restrict__ Out,
    long row, long obase)
{
    float x[48];
    const float4* __restrict__ Xr = (const float4*)(X + row * 48);
#pragma unroll
    for (int p = 0; p < 12; p++) {
        float4 v = Xr[p];
        x[p*4+0]=v.x; x[p*4+1]=v.y; x[p*4+2]=v.z; x[p*4+3]=v.w;
    }
#pragma unroll
    for (int h = 0; h < 3; h++) {
        float acc[16];
#pragma unroll
        for (int d = 0; d < 16; d++) {
            const int j = h*16 + d;
            float a = bias[j];
#pragma unroll
            for (int i = 0; i < 48; i++) a += x[i] * W[j*48 + i];
            acc[d] = a;
        }
        float4* __restrict__ dst = (float4*)(Out + (obase + ((long)h << 10)) * 16);
        dst[0] = make_float4(acc[0], acc[1], acc[2], acc[3]);
        dst[1] = make_float4(acc[4], acc[5], acc[6], acc[7]);
        dst[2] = make_float4(acc[8], acc[9], acc[10], acc[11]);
        dst[3] = make_float4(acc[12], acc[13], acc[14], acc[15]);
    }
}

// ---------------- Kernel 1: fused Q/K/V projections ----------------
__global__ __launch_bounds__(256) void proj_qkv(
    const float* __restrict__ Xq, const float* __restrict__ Xk, const float* __restrict__ Xv,
    const float* __restrict__ Wq, const float* __restrict__ bq,
    const float* __restrict__ Wk, const float* __restrict__ bk,
    const float* __restrict__ Wv, const float* __restrict__ bv,
    float* __restrict__ Qo, float* __restrict__ Ko, float* __restrict__ Vo)
{
    const long row = (long)blockIdx.x * 256 + threadIdx.x;   // 0..32767
    const long b = row >> 10, sp = row & 1023;
    const long obase = ((b*3) << 10) + sp;
    proj_row(Xq, Wq, bq, Qo, row, obase);
    proj_row(Xk, Wk, bk, Ko, row, obase);
    proj_row(Xv, Wv, bv, Vo, row, obase);
}

// ---------------- Kernel 2: fused attention ----------------
// Block = 256 threads = 16 q-rows x 16 k-lanes.
// Round-0's LDS staging (coalesced global float4 -> pitch-20 LDS, proven
// 2-way-free) + round-2's fully-static s[64] (all k/chunk loops unrolled,
// no scratch). A written with nontemporal scalar stores (write-once, keep
// out of L2). XCD-bijective block swizzle keeps one bh's K/V panel on one XCD.
__global__ __launch_bounds__(256) void attn(
    const float* __restrict__ Q, const float* __restrict__ K, const float* __restrict__ V,
    float* __restrict__ A, float* __restrict__ Hh)
{
    __shared__ float KV[256 * PITCH];   // 20 KB, reused for K then V

    const int blk  = blockIdx.x;
    const int virt = (blk & 7) * 768 + (blk >> 3);   // bijective, 6144 % 8 == 0
    const int bh   = virt >> 6;    // 0..95
    const int qt   = virt & 63;
    const int t    = threadIdx.x;
    const int qg   = t >> 4;       // 0..15 query row in tile
    const int kl   = t & 15;       // 0..15 k-lane

    const long base = (long)bh * 1024 * 16;
    const int  q    = qt * 16 + qg;

    float qv[16];
    load16(Q + base + (long)q * 16, qv);
#pragma unroll
    for (int d = 0; d < 16; d++) qv[d] *= 0.25f;   // 1/sqrt(16)

    const float4* __restrict__ Kb = (const float4*)(K + base);
    const float4* __restrict__ Vb = (const float4*)(V + base);

    // ---- Phase 1: scores. Chunk loop FULLY unrolled -> s[] static. ----
    float s[64];
#pragma unroll
    for (int c = 0; c < 4; c++) {
        __syncthreads();
#pragma unroll
        for (int i = 0; i < 4; i++) {
            const int f = t + 256*i;           // 0..1023
            const int r = f >> 2, p = f & 3;
            const float4 v = Kb[(c*256 + r)*4 + p];
            *(float4*)&KV[r*PITCH + p*4] = v;
        }
        __syncthreads();
#pragma unroll
        for (int i = 0; i < 16; i++) {
            const int r = i*16 + kl;
            const float4 a  = *(const float4*)&KV[r*PITCH + 0];
            const float4 b4 = *(const float4*)&KV[r*PITCH + 4];
            const float4 c4 = *(const float4*)&KV[r*PITCH + 8];
            const float4 d4 = *(const float4*)&KV[r*PITCH + 12];
            s[c*16 + i] = qv[0]*a.x   + qv[1]*a.y   + qv[2]*a.z   + qv[3]*a.w
                        + qv[4]*b4.x  + qv[5]*b4.y  + qv[6]*b4.z  + qv[7]*b4.w
                        + qv[8]*c4.x  + qv[9]*c4.y  + qv[10]*c4.z + qv[11]*c4.w
                        + qv[12]*d4.x + qv[13]*d4.y + qv[14]*d4.z + qv[15]*d4.w;
        }
    }

    // ---- softmax across the 16-lane q-group ----
    float m = -1e30f;
#pragma unroll
    for (int x = 0; x < 64; x++) m = fmaxf(m, s[x]);
#pragma unroll
    for (int mask = 1; mask < 16; mask <<= 1) m = fmaxf(m, __shfl_xor(m, mask, 16));
    float l = 0.f;
#pragma unroll
    for (int x = 0; x < 64; x++) { s[x] = __expf(s[x] - m); l += s[x]; }
#pragma unroll
    for (int mask = 1; mask < 16; mask <<= 1) l += __shfl_xor(l, mask, 16);
    const float inv = 1.0f / l;
#pragma unroll
    for (int x = 0; x < 64; x++) s[x] *= inv;

    // ---- Phase 2: write A (nontemporal) + accumulate PV via LDS V ----
    float o[16];
#pragma unroll
    for (int d = 0; d < 16; d++) o[d] = 0.f;
    float* Arow = A + ((long)bh * 1024 + q) * 1024;

#pragma unroll
    for (int c = 0; c < 4; c++) {
        __syncthreads();
#pragma unroll
        for (int i = 0; i < 4; i++) {
            const int f = t + 256*i;
            const int r = f >> 2, p = f & 3;
            const float4 v = Vb[(c*256 + r)*4 + p];
            *(float4*)&KV[r*PITCH + p*4] = v;
        }
        __syncthreads();
#pragma unroll
        for (int i = 0; i < 16; i++) {
            const int r = i*16 + kl;
            const float4 a  = *(const float4*)&KV[r*PITCH + 0];
            const float4 b4 = *(const float4*)&KV[r*PITCH + 4];
            const float4 c4 = *(const float4*)&KV[r*PITCH + 8];
            const float4 d4 = *(const float4*)&KV[r*PITCH + 12];
            const float p = s[c*16 + i];
            __builtin_nontemporal_store(p, Arow + c*256 + r);
            o[0]  += p*a.x;   o[1]  += p*a.y;   o[2]  += p*a.z;   o[3]  += p*a.w;
            o[4]  += p*b4.x;  o[5]  += p*b4.y;  o[6]  += p*b4.z;  o[7]  += p*b4.w;
            o[8]  += p*c4.x;  o[9]  += p*c4.y;  o[10] += p*c4.z;  o[11] += p*c4.w;
            o[12] += p*d4.x;  o[13] += p*d4.y;  o[14] += p*d4.z;  o[15] += p*d4.w;
        }
    }

#pragma unroll
    for (int mask = 1; mask < 16; mask <<= 1) {
#pragma unroll
        for (int d = 0; d < 16; d++) o[d] += __shfl_xor(o[d], mask, 16);
    }
    Hh[base + (long)q * 16 + kl] = o[kl];
}

// ---------------- Kernel 3: output projection ----------------
__global__ __launch_bounds__(256) void proj_out(
    const float* __restrict__ Hh, const float* __restrict__ Wh, const float* __restrict__ bhp,
    float* __restrict__ Hout)
{
    const long row = (long)blockIdx.x * 256 + threadIdx.x;
    const long b = row >> 10, sp = row & 1023;

    float x[48];
#pragma unroll
    for (int h = 0; h < 3; h++) {
        const float4* __restrict__ src = (const float4*)(Hh + (((b*3 + h) << 10) + sp) * 16);
#pragma unroll
        for (int p = 0; p < 4; p++) {
            float4 v = src[p];
            x[h*16 + p*4 + 0] = v.x; x[h*16 + p*4 + 1] = v.y;
            x[h*16 + p*4 + 2] = v.z; x[h*16 + p*4 + 3] = v.w;
        }
    }

    float4* __restrict__ dst = (float4*)(Hout + row * 48);
#pragma unroll
    for (int p4 = 0; p4 < 12; p4++) {
        float a4[4];
#pragma unroll
        for (int u = 0; u < 4; u++) {
            const int j = p4*4 + u;
            float a = bhp[j];
#pragma unroll
            for (int i = 0; i < 48; i++) a += x[i] * Wh[j*48 + i];
            a4[u] = a;
        }
        dst[p4] = make_float4(a4[0], a4[1], a4[2], a4[3]);
    }
}

extern "C" void kernel_launch(void* const* d_in, const int* in_sizes, int n_in,
                              void* d_out, int out_size, void* d_ws, size_t ws_size,
                              hipStream_t stream) {
    const float* Xq = (const float*)d_in[0];
    const float* Xk = (const float*)d_in[1];
    const float* Xv = (const float*)d_in[2];
    const float* Wq = (const float*)d_in[3];
    const float* bq = (const float*)d_in[4];
    const float* Wk = (const float*)d_in[5];
    const float* bk = (const float*)d_in[6];
    const float* Wv = (const float*)d_in[7];
    const float* bv = (const float*)d_in[8];
    const float* Wh = (const float*)d_in[9];
    const float* bh = (const float*)d_in[10];

    float* out = (float*)d_out;
    float* Hout = out;                    // [32,1024,48]
    float* Aout = out + HW_SZ;            // [32,3,1024,1024]

    float* ws = (float*)d_ws;
    float* Qw = ws;
    float* Kw = ws + HW_SZ;
    float* Vw = ws + 2*HW_SZ;
    float* Hw = ws + 3*HW_SZ;

    proj_qkv<<<NROWS/256, 256, 0, stream>>>(Xq, Xk, Xv, Wq, bq, Wk, bk, Wv, bv, Qw, Kw, Vw);
    attn<<<96*64, 256, 0, stream>>>(Qw, Kw, Vw, Aout, Hw);
    proj_out<<<NROWS/256, 256, 0, stream>>>(Hw, Wh, bh, Hout);
}

// Round 5
// 551.911 us; speedup vs baseline: 2.1258x; 1.2593x over previous
//
#include <hip/hip_runtime.h>
#include <math.h>

// CrossAttention  B=32, S=1024, D_MODEL=48, NUM_HEADS=3, D_K=16
// Outputs: H [32,1024,48] ++ A [32,3,1024,1024], fp32.

#define NROWS   32768      // B*S
#define HW_SZ   1572864L   // 96*1024*16 floats per Q/K/V/Hh buffer
#define PITCH   20         // LDS row pitch (floats): 2-way bank aliasing = free

__device__ __forceinline__ void load16(const float* __restrict__ p, float* r) {
    float4 a = ((const float4*)p)[0];
    float4 b = ((const float4*)p)[1];
    float4 c = ((const float4*)p)[2];
    float4 d = ((const float4*)p)[3];
    r[0]=a.x;  r[1]=a.y;  r[2]=a.z;  r[3]=a.w;
    r[4]=b.x;  r[5]=b.y;  r[6]=b.z;  r[7]=b.w;
    r[8]=c.x;  r[9]=c.y;  r[10]=c.z; r[11]=c.w;
    r[12]=d.x; r[13]=d.y; r[14]=d.z; r[15]=d.w;
}

// ---------------- Kernel 1: fused Q/K/V projections ----------------
// Thread = (matrix m, head h, row): 294912 threads, 1152 blocks (~4.5/CU).
// Each mh-group spans exactly 128 blocks, so mh = blockIdx.x >> 7 is an
// SGPR expression -> W/bias accesses are wave-uniform s_load broadcasts.
// 768 FMA/thread with 16-way ILP; X row in 48 VGPRs via float4 loads.
__global__ __launch_bounds__(256) void proj_qkv(
    const float* __restrict__ Xq, const float* __restrict__ Xk, const float* __restrict__ Xv,
    const float* __restrict__ Wq, const float* __restrict__ bq,
    const float* __restrict__ Wk, const float* __restrict__ bk,
    const float* __restrict__ Wv, const float* __restrict__ bv,
    float* __restrict__ Qo, float* __restrict__ Ko, float* __restrict__ Vo)
{
    const int mh = blockIdx.x >> 7;                 // 0..8, SGPR-uniform
    const int m  = mh / 3, h = mh % 3;
    const long row = ((long)(blockIdx.x & 127) << 8) | threadIdx.x;   // 0..32767

    const float* __restrict__ X    = (m == 0) ? Xq : ((m == 1) ? Xk : Xv);
    const float* __restrict__ W    = (m == 0) ? Wq : ((m == 1) ? Wk : Wv);
    const float* __restrict__ bias = (m == 0) ? bq : ((m == 1) ? bk : bv);
    float*       __restrict__ Out  = (m == 0) ? Qo : ((m == 1) ? Ko : Vo);

    float x[48];
    const float4* __restrict__ Xr = (const float4*)(X + row * 48);
#pragma unroll
    for (int p = 0; p < 12; p++) {
        float4 v = Xr[p];
        x[p*4+0]=v.x; x[p*4+1]=v.y; x[p*4+2]=v.z; x[p*4+3]=v.w;
    }

    float acc[16];
#pragma unroll
    for (int d = 0; d < 16; d++) {
        const int j = h*16 + d;
        float a = bias[j];
#pragma unroll
        for (int i = 0; i < 48; i++) a += x[i] * W[j*48 + i];
        acc[d] = a;
    }

    const long b = row >> 10, sp = row & 1023;
    float4* __restrict__ dst = (float4*)(Out + ((((b*3 + h) << 10) + sp) << 4));
    dst[0] = make_float4(acc[0],  acc[1],  acc[2],  acc[3]);
    dst[1] = make_float4(acc[4],  acc[5],  acc[6],  acc[7]);
    dst[2] = make_float4(acc[8],  acc[9],  acc[10], acc[11]);
    dst[3] = make_float4(acc[12], acc[13], acc[14], acc[15]);
}

// ---------------- Kernel 2: fused attention ----------------
// (unchanged from round 3, verified at ~250 µs: LDS-staged K/V, fully-static
// s[64], nontemporal A stores, XCD-bijective swizzle)
__global__ __launch_bounds__(256) void attn(
    const float* __restrict__ Q, const float* __restrict__ K, const float* __restrict__ V,
    float* __restrict__ A, float* __restrict__ Hh)
{
    __shared__ float KV[256 * PITCH];   // 20 KB, reused for K then V

    const int blk  = blockIdx.x;
    const int virt = (blk & 7) * 768 + (blk >> 3);   // bijective, 6144 % 8 == 0
    const int bh   = virt >> 6;    // 0..95
    const int qt   = virt & 63;
    const int t    = threadIdx.x;
    const int qg   = t >> 4;       // 0..15 query row in tile
    const int kl   = t & 15;       // 0..15 k-lane

    const long base = (long)bh * 1024 * 16;
    const int  q    = qt * 16 + qg;

    float qv[16];
    load16(Q + base + (long)q * 16, qv);
#pragma unroll
    for (int d = 0; d < 16; d++) qv[d] *= 0.25f;   // 1/sqrt(16)

    const float4* __restrict__ Kb = (const float4*)(K + base);
    const float4* __restrict__ Vb = (const float4*)(V + base);

    // ---- Phase 1: scores. Chunk loop FULLY unrolled -> s[] static. ----
    float s[64];
#pragma unroll
    for (int c = 0; c < 4; c++) {
        __syncthreads();
#pragma unroll
        for (int i = 0; i < 4; i++) {
            const int f = t + 256*i;           // 0..1023
            const int r = f >> 2, p = f & 3;
            const float4 v = Kb[(c*256 + r)*4 + p];
            *(float4*)&KV[r*PITCH + p*4] = v;
        }
        __syncthreads();
#pragma unroll
        for (int i = 0; i < 16; i++) {
            const int r = i*16 + kl;
            const float4 a  = *(const float4*)&KV[r*PITCH + 0];
            const float4 b4 = *(const float4*)&KV[r*PITCH + 4];
            const float4 c4 = *(const float4*)&KV[r*PITCH + 8];
            const float4 d4 = *(const float4*)&KV[r*PITCH + 12];
            s[c*16 + i] = qv[0]*a.x   + qv[1]*a.y   + qv[2]*a.z   + qv[3]*a.w
                        + qv[4]*b4.x  + qv[5]*b4.y  + qv[6]*b4.z  + qv[7]*b4.w
                        + qv[8]*c4.x  + qv[9]*c4.y  + qv[10]*c4.z + qv[11]*c4.w
                        + qv[12]*d4.x + qv[13]*d4.y + qv[14]*d4.z + qv[15]*d4.w;
        }
    }

    // ---- softmax across the 16-lane q-group ----
    float m = -1e30f;
#pragma unroll
    for (int x = 0; x < 64; x++) m = fmaxf(m, s[x]);
#pragma unroll
    for (int mask = 1; mask < 16; mask <<= 1) m = fmaxf(m, __shfl_xor(m, mask, 16));
    float l = 0.f;
#pragma unroll
    for (int x = 0; x < 64; x++) { s[x] = __expf(s[x] - m); l += s[x]; }
#pragma unroll
    for (int mask = 1; mask < 16; mask <<= 1) l += __shfl_xor(l, mask, 16);
    const float inv = 1.0f / l;
#pragma unroll
    for (int x = 0; x < 64; x++) s[x] *= inv;

    // ---- Phase 2: write A (nontemporal) + accumulate PV via LDS V ----
    float o[16];
#pragma unroll
    for (int d = 0; d < 16; d++) o[d] = 0.f;
    float* Arow = A + ((long)bh * 1024 + q) * 1024;

#pragma unroll
    for (int c = 0; c < 4; c++) {
        __syncthreads();
#pragma unroll
        for (int i = 0; i < 4; i++) {
            const int f = t + 256*i;
            const int r = f >> 2, p = f & 3;
            const float4 v = Vb[(c*256 + r)*4 + p];
            *(float4*)&KV[r*PITCH + p*4] = v;
        }
        __syncthreads();
#pragma unroll
        for (int i = 0; i < 16; i++) {
            const int r = i*16 + kl;
            const float4 a  = *(const float4*)&KV[r*PITCH + 0];
            const float4 b4 = *(const float4*)&KV[r*PITCH + 4];
            const float4 c4 = *(const float4*)&KV[r*PITCH + 8];
            const float4 d4 = *(const float4*)&KV[r*PITCH + 12];
            const float p = s[c*16 + i];
            __builtin_nontemporal_store(p, Arow + c*256 + r);
            o[0]  += p*a.x;   o[1]  += p*a.y;   o[2]  += p*a.z;   o[3]  += p*a.w;
            o[4]  += p*b4.x;  o[5]  += p*b4.y;  o[6]  += p*b4.z;  o[7]  += p*b4.w;
            o[8]  += p*c4.x;  o[9]  += p*c4.y;  o[10] += p*c4.z;  o[11] += p*c4.w;
            o[12] += p*d4.x;  o[13] += p*d4.y;  o[14] += p*d4.z;  o[15] += p*d4.w;
        }
    }

#pragma unroll
    for (int mask = 1; mask < 16; mask <<= 1) {
#pragma unroll
        for (int d = 0; d < 16; d++) o[d] += __shfl_xor(o[d], mask, 16);
    }
    Hh[base + (long)q * 16 + kl] = o[kl];
}

// ---------------- Kernel 3: output projection ----------------
// Thread = (out-col-group jg, row): 98304 threads, 384 blocks.
// jg = blockIdx.x >> 7 (128 blocks per group) -> SGPR-uniform W offsets.
__global__ __launch_bounds__(256) void proj_out(
    const float* __restrict__ Hh, const float* __restrict__ Wh, const float* __restrict__ bhp,
    float* __restrict__ Hout)
{
    const int jg = blockIdx.x >> 7;                 // 0..2, SGPR-uniform
    const long row = ((long)(blockIdx.x & 127) << 8) | threadIdx.x;
    const long b = row >> 10, sp = row & 1023;

    float x[48];
#pragma unroll
    for (int h = 0; h < 3; h++) {
        const float4* __restrict__ src = (const float4*)(Hh + ((((b*3 + h) << 10) + sp) << 4));
#pragma unroll
        for (int p = 0; p < 4; p++) {
            float4 v = src[p];
            x[h*16 + p*4 + 0] = v.x; x[h*16 + p*4 + 1] = v.y;
            x[h*16 + p*4 + 2] = v.z; x[h*16 + p*4 + 3] = v.w;
        }
    }

    float acc[16];
#pragma unroll
    for (int d = 0; d < 16; d++) {
        const int j = jg*16 + d;
        float a = bhp[j];
#pragma unroll
        for (int i = 0; i < 48; i++) a += x[i] * Wh[j*48 + i];
        acc[d] = a;
    }

    float4* __restrict__ dst = (float4*)(Hout + row * 48 + jg * 16);
    dst[0] = make_float4(acc[0],  acc[1],  acc[2],  acc[3]);
    dst[1] = make_float4(acc[4],  acc[5],  acc[6],  acc[7]);
    dst[2] = make_float4(acc[8],  acc[9],  acc[10], acc[11]);
    dst[3] = make_float4(acc[12], acc[13], acc[14], acc[15]);
}

extern "C" void kernel_launch(void* const* d_in, const int* in_sizes, int n_in,
                              void* d_out, int out_size, void* d_ws, size_t ws_size,
                              hipStream_t stream) {
    const float* Xq = (const float*)d_in[0];
    const float* Xk = (const float*)d_in[1];
    const float* Xv = (const float*)d_in[2];
    const float* Wq = (const float*)d_in[3];
    const float* bq = (const float*)d_in[4];
    const float* Wk = (const float*)d_in[5];
    const float* bk = (const float*)d_in[6];
    const float* Wv = (const float*)d_in[7];
    const float* bv = (const float*)d_in[8];
    const float* Wh = (const float*)d_in[9];
    const float* bh = (const float*)d_in[10];

    float* out = (float*)d_out;
    float* Hout = out;                    // [32,1024,48]
    float* Aout = out + HW_SZ;            // [32,3,1024,1024]

    float* ws = (float*)d_ws;
    float* Qw = ws;
    float* Kw = ws + HW_SZ;
    float* Vw = ws + 2*HW_SZ;
    float* Hw = ws + 3*HW_SZ;

    proj_qkv<<<1152, 256, 0, stream>>>(Xq, Xk, Xv, Wq, bq, Wk, bk, Wv, bv, Qw, Kw, Vw);
    attn<<<96*64, 256, 0, stream>>>(Qw, Kw, Vw, Aout, Hw);
    proj_out<<<384, 256, 0, stream>>>(Hw, Wh, bh, Hout);
}